// Round 3
// baseline (251.270 us; speedup 1.0000x reference)
//
#include <hip/hip_runtime.h>

#define M_DIM 512
#define N_DIM 4096
#define K_DIM 4096
#define SPLITK 4
#define KC (K_DIM / SPLITK)   // 1024
#define NTILES 128            // (M/128)*(N/128)

typedef __attribute__((ext_vector_type(4))) float f32x4;

// ---- ws layout (bytes) ----
// [0,1024)      float part_x[256]
// [1024,5120)   float part_w[1024]
// [5120,5128)   float amax_final[2]
// [6144,6656)   int   tile_cnt[128]
// [8192, +2MB)  xq fp8
// [then, +16MB) wq fp8
// [then, +32MB) fp32 partials: 128 tiles * 4 splits * 16384 floats
#define PART_X_OFF 0
#define PART_X_N   256
#define PART_W_OFF 256
#define PART_W_N   1024
#define AMAX_OFF   1280
#define CNT_BYTE_OFF 6144
#define XQ_BYTE_OFF 8192
#define WQ_BYTE_OFF (XQ_BYTE_OFF + M_DIM * K_DIM)
#define PARTIAL_BYTE_OFF (WQ_BYTE_OFF + N_DIM * K_DIM)

// ---------------------------------------------------------------- amax ------
__global__ __launch_bounds__(256) void amax_kernel(
    const float4* __restrict__ x4, const float4* __restrict__ w4,
    float* __restrict__ ws_f, int* __restrict__ cnt) {
    const int b = blockIdx.x;
    if (b == 0 && threadIdx.x < NTILES) cnt[threadIdx.x] = 0;  // gemm arrival ctrs
    float m = 0.0f;
    if (b < PART_X_N) {  // x: 256 blocks
        const int n4 = M_DIM * K_DIM / 4, stride = PART_X_N * 256;
        for (int i = b * 256 + threadIdx.x; i < n4; i += stride) {
            float4 a = x4[i];
            m = fmaxf(m, fmaxf(fmaxf(fabsf(a.x), fabsf(a.y)),
                               fmaxf(fabsf(a.z), fabsf(a.w))));
        }
    } else {             // w: 1024 blocks
        const int n4 = N_DIM * K_DIM / 4, stride = PART_W_N * 256;
        for (int i = (b - PART_X_N) * 256 + threadIdx.x; i < n4; i += stride) {
            float4 a = w4[i];
            m = fmaxf(m, fmaxf(fmaxf(fabsf(a.x), fabsf(a.y)),
                               fmaxf(fabsf(a.z), fabsf(a.w))));
        }
    }
    for (int off = 32; off > 0; off >>= 1)
        m = fmaxf(m, __shfl_down(m, off, 64));
    __shared__ float sm[4];
    if ((threadIdx.x & 63) == 0) sm[threadIdx.x >> 6] = m;
    __syncthreads();
    if (threadIdx.x == 0) {
        m = fmaxf(fmaxf(sm[0], sm[1]), fmaxf(sm[2], sm[3]));
        ws_f[(b < PART_X_N) ? (PART_X_OFF + b) : (PART_W_OFF + b - PART_X_N)] = m;
    }
}

// ------------------------------------------------------------- quantize -----
// e2m1 codebook values as OCP e4m3fn bytes (exact): 0,0.5,1,1.5,2,3,4,6.
// Midpoint ties -> smaller magnitude (matches jnp.argmin first-occurrence).
__device__ __forceinline__ unsigned int q1(float x, float s) {
    float a = fabsf(x) * s;
    unsigned int b;
    if      (a <= 0.25f) b = 0x00u;  // 0.0
    else if (a <= 0.75f) b = 0x30u;  // 0.5
    else if (a <= 1.25f) b = 0x38u;  // 1.0
    else if (a <= 1.75f) b = 0x3Cu;  // 1.5
    else if (a <= 2.5f)  b = 0x40u;  // 2.0
    else if (a <= 3.5f)  b = 0x44u;  // 3.0
    else if (a <= 5.0f)  b = 0x48u;  // 4.0
    else                 b = 0x4Cu;  // 6.0 (also handles clip)
    return b | ((__float_as_uint(x) >> 24) & 0x80u);
}
__device__ __forceinline__ unsigned int qpack4(float4 v, float s) {
    return q1(v.x, s) | (q1(v.y, s) << 8) | (q1(v.z, s) << 16) | (q1(v.w, s) << 24);
}

__global__ __launch_bounds__(256) void quant_kernel(
    const float4* __restrict__ x4, const float4* __restrict__ w4,
    float* __restrict__ ws_f, unsigned char* __restrict__ ws_b) {
    const int b = blockIdx.x, t = threadIdx.x;
    const bool is_x = b < 512;
    float m = 0.0f;
    if (is_x) {
        m = ws_f[PART_X_OFF + t];
    } else {
        for (int i = t; i < PART_W_N; i += 256)
            m = fmaxf(m, ws_f[PART_W_OFF + i]);
    }
    for (int off = 32; off > 0; off >>= 1)
        m = fmaxf(m, __shfl_down(m, off, 64));
    __shared__ float sm[4];
    if ((t & 63) == 0) sm[t >> 6] = m;
    __syncthreads();
    m = fmaxf(fmaxf(sm[0], sm[1]), fmaxf(sm[2], sm[3]));
    float amax = fmaxf(m, 1e-12f);
    float s = 6.0f / amax;
    if (t == 0 && b == 0)   ws_f[AMAX_OFF + 0] = amax;
    if (t == 0 && b == 512) ws_f[AMAX_OFF + 1] = amax;

    const float4* src = is_x ? x4 : w4;
    unsigned char* dstb = ws_b + (is_x ? XQ_BYTE_OFF : WQ_BYTE_OFF);
    const int idx16 = (is_x ? b : b - 512) * 256 + t;
    const float4* p = src + (size_t)idx16 * 4;
    uint4 o;
    o.x = qpack4(p[0], s);
    o.y = qpack4(p[1], s);
    o.z = qpack4(p[2], s);
    o.w = qpack4(p[3], s);
    ((uint4*)dstb)[idx16] = o;
}

// ----------------------------------------------------------------- GEMM -----
__device__ __forceinline__ void async_copy16(const void* g, void* l) {
    __builtin_amdgcn_global_load_lds(
        (const __attribute__((address_space(1))) unsigned int*)g,
        (__attribute__((address_space(3))) unsigned int*)l, 16, 0, 0);
}

// C[m,n] = sum_k A[m,k]*B[n,k], fp8 operands (codebook units).
// 128x128 tile, BK=64, 4 waves of 64x64. Split-K=4 via arrival counters:
// every block stores fp32 partial (fragment-order, float4), release-fences,
// bumps the tile counter; the last block acquire-fences, reduces 4 partials,
// scales by inv_x*inv_w, writes C. No atomics on C, no C memset needed.
__global__ __launch_bounds__(256, 4) void gemm_kernel(
    const unsigned char* __restrict__ A, const unsigned char* __restrict__ B,
    float* __restrict__ C, const float* __restrict__ amax2,
    float* __restrict__ parts, int* __restrict__ cnt) {
    __shared__ __align__(16) unsigned char As[128 * 64];
    __shared__ __align__(16) unsigned char Bs[128 * 64];

    const int bid  = blockIdx.x;
    const int sk   = bid & (SPLITK - 1);
    const int t2   = bid >> 2;         // tile id 0..127
    const int bm   = (t2 & 3) * 128;   // M/128 = 4
    const int bn   = (t2 >> 2) * 128;  // N/128 = 32
    const int tid  = threadIdx.x;
    const int lane = tid & 63;
    const int wave = tid >> 6;
    const int wm   = (wave >> 1) * 64;
    const int wn   = (wave & 1) * 64;
    const int t15  = lane & 15;
    const int quad = lane >> 4;

    // staging: slot c = tid + j*256 -> LDS byte c*16; physical (row=c>>2,
    // col=c&3) loads global col (c&3)^((row>>1)&3)  [XOR swizzle]
    const int r0 = tid >> 2, r1 = r0 + 64;
    const int c0 = (tid & 3) ^ ((r0 >> 1) & 3);
    const int c1 = (tid & 3) ^ ((r1 >> 1) & 3);
    const unsigned char* a0 = A + (size_t)(bm + r0) * K_DIM + sk * KC + c0 * 16;
    const unsigned char* a1 = A + (size_t)(bm + r1) * K_DIM + sk * KC + c1 * 16;
    const unsigned char* b0 = B + (size_t)(bn + r0) * K_DIM + sk * KC + c0 * 16;
    const unsigned char* b1 = B + (size_t)(bn + r1) * K_DIM + sk * KC + c1 * 16;
    unsigned char* asl0 = As + wave * 1024;
    unsigned char* asl1 = As + 4096 + wave * 1024;
    unsigned char* bsl0 = Bs + wave * 1024;
    unsigned char* bsl1 = Bs + 4096 + wave * 1024;

    f32x4 acc[4][4] = {};

    for (int k = 0; k < KC; k += 64) {
        async_copy16(a0 + k, asl0);
        async_copy16(a1 + k, asl1);
        async_copy16(b0 + k, bsl0);
        async_copy16(b1 + k, bsl1);
        __syncthreads();

        long af[2][4], bf[2][4];
#pragma unroll
        for (int h = 0; h < 2; h++)
#pragma unroll
            for (int i = 0; i < 4; i++) {
                const int lc = (quad >> 1) + h * 2;
                const int mrow = wm + i * 16 + t15;
                const int nrow = wn + i * 16 + t15;
                af[h][i] = *(const long*)(As + mrow * 64 +
                                          (lc ^ ((mrow >> 1) & 3)) * 16 +
                                          (quad & 1) * 8);
                bf[h][i] = *(const long*)(Bs + nrow * 64 +
                                          (lc ^ ((nrow >> 1) & 3)) * 16 +
                                          (quad & 1) * 8);
            }
#pragma unroll
        for (int h = 0; h < 2; h++)
#pragma unroll
            for (int i = 0; i < 4; i++)
#pragma unroll
                for (int j = 0; j < 4; j++)
                    acc[i][j] = __builtin_amdgcn_mfma_f32_16x16x32_fp8_fp8(
                        af[h][i], bf[h][j], acc[i][j], 0, 0, 0);
        __syncthreads();
    }

    // ---- split-K completion ----
    // partial layout (fragment order): float4 index f = ((wave*4+i)*4+j)*64+lane
    float4* myp = (float4*)(parts + ((size_t)t2 * SPLITK + sk) * 16384);
#pragma unroll
    for (int i = 0; i < 4; i++)
#pragma unroll
        for (int j = 0; j < 4; j++) {
            float4 v = {acc[i][j][0], acc[i][j][1], acc[i][j][2], acc[i][j][3]};
            myp[((wave * 4 + i) * 4 + j) * 64 + lane] = v;
        }
    __threadfence();       // release: partials visible at device scope
    __syncthreads();       // all waves' stores+fences done before signal
    __shared__ int s_old;
    if (tid == 0) s_old = atomicAdd(&cnt[t2], 1);
    __syncthreads();
    if (s_old != SPLITK - 1) return;

    __threadfence();       // acquire: invalidate stale cache lines
    const float cs = (1.0f / (6.0f / fmaxf(amax2[0], 1e-12f))) *
                     (1.0f / (6.0f / fmaxf(amax2[1], 1e-12f)));
    const float4* q = (const float4*)(parts + (size_t)t2 * SPLITK * 16384);
    for (int f = tid; f < 4096; f += 256) {
        float4 v0 = q[f], v1 = q[4096 + f], v2 = q[8192 + f], v3 = q[12288 + f];
        float r0f = (v0.x + v1.x + v2.x + v3.x) * cs;
        float r1f = (v0.y + v1.y + v2.y + v3.y) * cs;
        float r2f = (v0.z + v1.z + v2.z + v3.z) * cs;
        float r3f = (v0.w + v1.w + v2.w + v3.w) * cs;
        // decode fragment coords -> C
        const int ln = f & 63, jj = (f >> 6) & 3, ii = (f >> 8) & 3, wv = f >> 10;
        const int row = bm + (wv >> 1) * 64 + ii * 16 + (ln >> 4) * 4;
        const int col = bn + (wv & 1) * 64 + jj * 16 + (ln & 15);
        float* cp = C + (size_t)row * N_DIM + col;
        cp[0] = r0f;
        cp[N_DIM] = r1f;
        cp[2 * N_DIM] = r2f;
        cp[3 * N_DIM] = r3f;
    }
}

// ---------------------------------------------------------------- launch ----
extern "C" void kernel_launch(void* const* d_in, const int* in_sizes, int n_in,
                              void* d_out, int out_size, void* d_ws, size_t ws_size,
                              hipStream_t stream) {
    const float* x = (const float*)d_in[0];   // [512, 4096]
    const float* w = (const float*)d_in[1];   // [4096, 4096]
    float* out = (float*)d_out;               // [512, 4096]

    float* ws_f = (float*)d_ws;
    unsigned char* ws_b = (unsigned char*)d_ws;
    int* cnt = (int*)(ws_b + CNT_BYTE_OFF);
    const unsigned char* xq = ws_b + XQ_BYTE_OFF;
    const unsigned char* wq = ws_b + WQ_BYTE_OFF;
    float* parts = (float*)(ws_b + PARTIAL_BYTE_OFF);

    amax_kernel<<<PART_X_N + PART_W_N, 256, 0, stream>>>(
        (const float4*)x, (const float4*)w, ws_f, cnt);
    quant_kernel<<<512 + 4096, 256, 0, stream>>>(
        (const float4*)x, (const float4*)w, ws_f, ws_b);
    gemm_kernel<<<NTILES * SPLITK, 256, 0, stream>>>(
        xq, wq, out, ws_f + AMAX_OFF, parts, cnt);
}

// Round 4
// 157.773 us; speedup vs baseline: 1.5926x; 1.5926x over previous
//
#include <hip/hip_runtime.h>

#define M_DIM 512
#define N_DIM 4096
#define K_DIM 4096

typedef __attribute__((ext_vector_type(4))) float f32x4;

// ---- ws layout (bytes) ----
// [0,1024)      float part_x[256]
// [1024,5120)   float part_w[1024]
// [5120,5128)   float amax_final[2]
// [8192, +2MB)  xq fp8
// [then, +16MB) wq fp8
#define PART_X_OFF 0
#define PART_X_N   256
#define PART_W_OFF 256
#define PART_W_N   1024
#define AMAX_OFF   1280
#define XQ_BYTE_OFF 8192
#define WQ_BYTE_OFF (XQ_BYTE_OFF + M_DIM * K_DIM)

// ---------------------------------------------------------------- amax ------
__global__ __launch_bounds__(256) void amax_kernel(
    const float4* __restrict__ x4, const float4* __restrict__ w4,
    float* __restrict__ ws_f) {
    const int b = blockIdx.x;
    float m = 0.0f;
    if (b < PART_X_N) {  // x: 256 blocks
        const int n4 = M_DIM * K_DIM / 4, stride = PART_X_N * 256;
        for (int i = b * 256 + threadIdx.x; i < n4; i += stride) {
            float4 a = x4[i];
            m = fmaxf(m, fmaxf(fmaxf(fabsf(a.x), fabsf(a.y)),
                               fmaxf(fabsf(a.z), fabsf(a.w))));
        }
    } else {             // w: 1024 blocks
        const int n4 = N_DIM * K_DIM / 4, stride = PART_W_N * 256;
        for (int i = (b - PART_X_N) * 256 + threadIdx.x; i < n4; i += stride) {
            float4 a = w4[i];
            m = fmaxf(m, fmaxf(fmaxf(fabsf(a.x), fabsf(a.y)),
                               fmaxf(fabsf(a.z), fabsf(a.w))));
        }
    }
    for (int off = 32; off > 0; off >>= 1)
        m = fmaxf(m, __shfl_down(m, off, 64));
    __shared__ float sm[4];
    if ((threadIdx.x & 63) == 0) sm[threadIdx.x >> 6] = m;
    __syncthreads();
    if (threadIdx.x == 0) {
        m = fmaxf(fmaxf(sm[0], sm[1]), fmaxf(sm[2], sm[3]));
        ws_f[(b < PART_X_N) ? (PART_X_OFF + b) : (PART_W_OFF + b - PART_X_N)] = m;
    }
}

// ------------------------------------------------------------- quantize -----
// e2m1 codebook values as OCP e4m3fn bytes (exact): 0,0.5,1,1.5,2,3,4,6.
// Midpoint ties -> smaller magnitude (matches jnp.argmin first-occurrence).
__device__ __forceinline__ unsigned int q1(float x, float s) {
    float a = fabsf(x) * s;
    unsigned int b;
    if      (a <= 0.25f) b = 0x00u;  // 0.0
    else if (a <= 0.75f) b = 0x30u;  // 0.5
    else if (a <= 1.25f) b = 0x38u;  // 1.0
    else if (a <= 1.75f) b = 0x3Cu;  // 1.5
    else if (a <= 2.5f)  b = 0x40u;  // 2.0
    else if (a <= 3.5f)  b = 0x44u;  // 3.0
    else if (a <= 5.0f)  b = 0x48u;  // 4.0
    else                 b = 0x4Cu;  // 6.0 (also handles clip)
    return b | ((__float_as_uint(x) >> 24) & 0x80u);
}
__device__ __forceinline__ unsigned int qpack4(float4 v, float s) {
    return q1(v.x, s) | (q1(v.y, s) << 8) | (q1(v.z, s) << 16) | (q1(v.w, s) << 24);
}

__global__ __launch_bounds__(256) void quant_kernel(
    const float4* __restrict__ x4, const float4* __restrict__ w4,
    float* __restrict__ ws_f, unsigned char* __restrict__ ws_b) {
    const int b = blockIdx.x, t = threadIdx.x;
    const bool is_x = b < 512;
    float m = 0.0f;
    if (is_x) {
        m = ws_f[PART_X_OFF + t];
    } else {
        for (int i = t; i < PART_W_N; i += 256)
            m = fmaxf(m, ws_f[PART_W_OFF + i]);
    }
    for (int off = 32; off > 0; off >>= 1)
        m = fmaxf(m, __shfl_down(m, off, 64));
    __shared__ float sm[4];
    if ((t & 63) == 0) sm[t >> 6] = m;
    __syncthreads();
    m = fmaxf(fmaxf(sm[0], sm[1]), fmaxf(sm[2], sm[3]));
    float amax = fmaxf(m, 1e-12f);
    float s = 6.0f / amax;
    if (t == 0 && b == 0)   ws_f[AMAX_OFF + 0] = amax;
    if (t == 0 && b == 512) ws_f[AMAX_OFF + 1] = amax;

    const float4* src = is_x ? x4 : w4;
    unsigned char* dstb = ws_b + (is_x ? XQ_BYTE_OFF : WQ_BYTE_OFF);
    const int idx16 = (is_x ? b : b - 512) * 256 + t;
    const float4* p = src + (size_t)idx16 * 4;
    uint4 o;
    o.x = qpack4(p[0], s);
    o.y = qpack4(p[1], s);
    o.z = qpack4(p[2], s);
    o.w = qpack4(p[3], s);
    ((uint4*)dstb)[idx16] = o;
}

// ----------------------------------------------------------------- GEMM -----
__device__ __forceinline__ void async_copy16(const void* g, void* l) {
    __builtin_amdgcn_global_load_lds(
        (const __attribute__((address_space(1))) unsigned int*)g,
        (__attribute__((address_space(3))) unsigned int*)l, 16, 0, 0);
}

// C[m,n] = sum_k A[m,k]*B[n,k], fp8 operands (codebook units), FULL K per
// block (no split-K, no atomics, no fences). 64x64 tile -> 8*64 = 512
// blocks (2/CU). 4 waves in 2x2, each 32x32 via 2x2 of 16x16x32 fp8, BK=64.
// XCD-aware mapping: bid&7 picks the N-slice so each XCD's L2 (4MB) holds
// its 2MB W-slice + 2MB x. LDS 16B-granule XOR swizzle (4-way residual
// conflict is the floor for this staging geometry).
__global__ __launch_bounds__(256, 2) void gemm_kernel(
    const unsigned char* __restrict__ A, const unsigned char* __restrict__ B,
    float* __restrict__ C, const float* __restrict__ amax2) {
    __shared__ __align__(16) unsigned char As[64 * 64];
    __shared__ __align__(16) unsigned char Bs[64 * 64];

    const int bid  = blockIdx.x;
    // bid = mt*64 + g*8 + x : x = XCD slice, g = n-subtile, mt = m-tile
    const int bm   = (bid >> 6) * 64;
    const int bn   = ((bid & 7) * 8 + ((bid >> 3) & 7)) * 64;
    const int tid  = threadIdx.x;
    const int lane = tid & 63;
    const int wave = tid >> 6;
    const int wm   = (wave >> 1) * 32;
    const int wn   = (wave & 1) * 32;
    const int t15  = lane & 15;
    const int quad = lane >> 4;

    const float cs = (1.0f / (6.0f / fmaxf(amax2[0], 1e-12f))) *
                     (1.0f / (6.0f / fmaxf(amax2[1], 1e-12f)));

    // staging: slot c = tid -> LDS byte c*16, physical (row=c>>2, pcol=c&3);
    // physical pcol holds global 16B-col (pcol ^ (row&3))
    const int srow = tid >> 2;
    const int sgc  = (tid & 3) ^ (srow & 3);
    const unsigned char* ag = A + (size_t)(bm + srow) * K_DIM + sgc * 16;
    const unsigned char* bg = B + (size_t)(bn + srow) * K_DIM + sgc * 16;
    unsigned char* asl = As + wave * 1024;  // lanes write base + lane*16
    unsigned char* bsl = Bs + wave * 1024;

    f32x4 acc[2][2] = {};

    for (int k = 0; k < K_DIM; k += 64) {
        async_copy16(ag + k, asl);
        async_copy16(bg + k, bsl);
        __syncthreads();

        long af[2][2], bf[2][2];
#pragma unroll
        for (int h = 0; h < 2; h++)
#pragma unroll
            for (int i = 0; i < 2; i++) {
                const int gc = h * 2 + (quad >> 1);   // global 16B col of frag
                const int mrow = wm + i * 16 + t15;
                const int nrow = wn + i * 16 + t15;
                af[h][i] = *(const long*)(As + mrow * 64 +
                                          (gc ^ (mrow & 3)) * 16 +
                                          (quad & 1) * 8);
                bf[h][i] = *(const long*)(Bs + nrow * 64 +
                                          (gc ^ (nrow & 3)) * 16 +
                                          (quad & 1) * 8);
            }
#pragma unroll
        for (int h = 0; h < 2; h++)
#pragma unroll
            for (int i = 0; i < 2; i++)
#pragma unroll
                for (int j = 0; j < 2; j++)
                    acc[i][j] = __builtin_amdgcn_mfma_f32_16x16x32_fp8_fp8(
                        af[h][i], bf[h][j], acc[i][j], 0, 0, 0);
        __syncthreads();
    }

    // C/D layout: col = lane&15 (n), row = quad*4 + reg (m). Plain stores.
#pragma unroll
    for (int i = 0; i < 2; i++)
#pragma unroll
        for (int j = 0; j < 2; j++) {
            const int m0 = bm + wm + i * 16 + quad * 4;
            const int n0 = bn + wn + j * 16 + t15;
#pragma unroll
            for (int r = 0; r < 4; r++)
                C[(size_t)(m0 + r) * N_DIM + n0] = acc[i][j][r] * cs;
        }
}

// ---------------------------------------------------------------- launch ----
extern "C" void kernel_launch(void* const* d_in, const int* in_sizes, int n_in,
                              void* d_out, int out_size, void* d_ws, size_t ws_size,
                              hipStream_t stream) {
    const float* x = (const float*)d_in[0];   // [512, 4096]
    const float* w = (const float*)d_in[1];   // [4096, 4096]
    float* out = (float*)d_out;               // [512, 4096]

    float* ws_f = (float*)d_ws;
    unsigned char* ws_b = (unsigned char*)d_ws;
    const unsigned char* xq = ws_b + XQ_BYTE_OFF;
    const unsigned char* wq = ws_b + WQ_BYTE_OFF;

    amax_kernel<<<PART_X_N + PART_W_N, 256, 0, stream>>>(
        (const float4*)x, (const float4*)w, ws_f);
    quant_kernel<<<512 + 4096, 256, 0, stream>>>(
        (const float4*)x, (const float4*)w, ws_f, ws_b);
    gemm_kernel<<<(M_DIM / 64) * (N_DIM / 64), 256, 0, stream>>>(
        xq, wq, out, ws_f + AMAX_OFF);
}